// Round 3
// baseline (778.526 us; speedup 1.0000x reference)
//
#include <hip/hip_runtime.h>
#include <hip/hip_cooperative_groups.h>
#include <math.h>

namespace cg = cooperative_groups;

// exp(-2*pi*r^2) == exp2(-L*r^2)
#define LCONST 9.064720283654388f
#define INV2L  (1.0f / (2.0f * LCONST))
#define RC     1.6f                       // cutoff: exp(-2pi*2.56) ~ 1.1e-7
#define SCALE  4.76837158203125e-4f       // A * V / 1024 = 8*(1000/16384)/1024

// ws layout (bytes)
#define O_PSS   0u          // 17408 float4  sorted sources (ent 0 = C, 1..16 = C1 batches)
#define O_PDS   278528u     // 16384 float4  sorted, folded grid points
#define O_THC   540672u     // 16384 float   theta_C per sorted grid point
#define O_SH    606208u     // 17*384 int    source histograms
#define O_KH    632320u     // 384 int       grid-point histogram
#define O_OFF   633856u     // 17*385 int    source bucket offsets (+sentinel)
#define O_OFFK  660036u     // 385 int
#define O_CUR   661576u     // 17*384 int    scatter cursors
#define O_CURK  687688u     // 384 int
#define O_PROD  689224u     // 16 float

struct Ptrs {
    float4* PSs; float4* PDs; float* thc;
    int *SH, *KH, *OFF, *OFFK, *CUR, *CURK;
    float* prod;
};

__device__ __forceinline__ Ptrs mk(char* ws) {
    Ptrs p;
    p.PSs  = (float4*)(ws + O_PSS);
    p.PDs  = (float4*)(ws + O_PDS);
    p.thc  = (float*)(ws + O_THC);
    p.SH   = (int*)(ws + O_SH);
    p.KH   = (int*)(ws + O_KH);
    p.OFF  = (int*)(ws + O_OFF);
    p.OFFK = (int*)(ws + O_OFFK);
    p.CUR  = (int*)(ws + O_CUR);
    p.CURK = (int*)(ws + O_CURK);
    p.prod = (float*)(ws + O_PROD);
    return p;
}

__device__ __forceinline__ float fexp2(float x) { return __builtin_amdgcn_exp2f(x); }

__device__ __forceinline__ int ckey(float y, float z) {
    int yc = (int)(y * 0.6f);  yc = yc < 0 ? 0 : (yc > 5 ? 5 : yc);
    int zb = (int)(z * 6.4f);  zb = zb < 0 ? 0 : (zb > 63 ? 63 : zb);
    return (yc << 6) + zb;
}

__device__ __forceinline__ void load_pt(const float* C1, const float* C, const float* dom,
                                        int i, int& ent, float& x, float& y, float& z) {
    const float* p;
    if (i < 17408) {
        int s = i >> 10, n = i & 1023;
        p = (s == 0) ? (C + 3 * n) : (C1 + 3 * (((s - 1) << 10) + n));
        ent = s;
    } else {
        p = dom + 3 * (i - 17408);
        ent = -1;
    }
    x = p[0]; y = p[1]; z = p[2];
}

__device__ __forceinline__ void do_hist(Ptrs P, const float* C1, const float* C,
                                        const float* dom, int i) {
    int ent; float x, y, z; load_pt(C1, C, dom, i, ent, x, y, z);
    int key = ckey(y, z);
    if (ent >= 0) atomicAdd(P.SH + ent * 384 + key, 1);
    else          atomicAdd(P.KH + key, 1);
}

__device__ __forceinline__ void do_scan(Ptrs P, int w, int lane) {
    const int* src = (w < 17) ? P.SH + w * 384 : P.KH;
    int* off = (w < 17) ? P.OFF + w * 385 : P.OFFK;
    int* cur = (w < 17) ? P.CUR + w * 384 : P.CURK;
    int c[6], pre[6], tot = 0, base = lane * 6;
    #pragma unroll
    for (int j = 0; j < 6; ++j) { c[j] = src[base + j]; pre[j] = tot; tot += c[j]; }
    int incl = tot;
    for (int o = 1; o < 64; o <<= 1) { int t = __shfl_up(incl, o, 64); if (lane >= o) incl += t; }
    int excl = incl - tot;
    #pragma unroll
    for (int j = 0; j < 6; ++j) { off[base + j] = excl + pre[j]; cur[base + j] = excl + pre[j]; }
    if (lane == 63) off[384] = incl;
}

__device__ __forceinline__ void do_scat(Ptrs P, const float* C1, const float* C,
                                        const float* dom, int i) {
    int ent; float x, y, z; load_pt(C1, C, dom, i, ent, x, y, z);
    int key = ckey(y, z);
    float q = x * x + y * y + z * z;
    if (ent >= 0) {
        int pos = atomicAdd(P.CUR + ent * 384 + key, 1);
        P.PSs[(ent << 10) + pos] = make_float4(x, y, z, -LCONST * q);
    } else {
        int pos = atomicAdd(P.CURK + key, 1);
        P.PDs[pos] = make_float4(2.0f * LCONST * x, 2.0f * LCONST * y, 2.0f * LCONST * z,
                                 -LCONST * q);
    }
}

__device__ __forceinline__ void wave_range(float y, float z, int& yc0, int& yc1,
                                           int& zb0, int& zb1) {
    float ymn = y, ymx = y, zmn = z, zmx = z;
    for (int o = 32; o; o >>= 1) {
        ymn = fminf(ymn, __shfl_xor(ymn, o, 64)); ymx = fmaxf(ymx, __shfl_xor(ymx, o, 64));
        zmn = fminf(zmn, __shfl_xor(zmn, o, 64)); zmx = fmaxf(zmx, __shfl_xor(zmx, o, 64));
    }
    yc0 = max(0, (int)floorf((ymn - RC) * 0.6f));
    yc1 = min(5, (int)floorf((ymx + RC) * 0.6f));
    zb0 = max(0, (int)floorf((zmn - RC) * 6.4f));
    zb1 = min(63, (int)floorf((zmx + RC) * 6.4f));
    yc0 = __builtin_amdgcn_readfirstlane(yc0); yc1 = __builtin_amdgcn_readfirstlane(yc1);
    zb0 = __builtin_amdgcn_readfirstlane(zb0); zb1 = __builtin_amdgcn_readfirstlane(zb1);
}

__device__ __forceinline__ float theta_acc(const float4* __restrict__ P,
                                           const int* __restrict__ otab, float4 d,
                                           int yc0, int yc1, int zb0, int zb1,
                                           int c, int nc) {
    float acc = 0.0f;
    for (int yc = yc0; yc <= yc1; ++yc) {
        int n0 = otab[(yc << 6) + zb0];
        int n1 = otab[(yc << 6) + zb1 + 1];
        int len = n1 - n0;
        int lo = n0 + (len * c) / nc, hi = n0 + (len * (c + 1)) / nc;
        #pragma unroll 4
        for (int n = lo; n < hi; ++n) {
            float4 p = P[n];
            acc += fexp2(fmaf(d.x, p.x, fmaf(d.y, p.y, fmaf(d.z, p.z, d.w + p.w))));
        }
    }
    return acc;
}

__device__ __forceinline__ void do_thc(Ptrs P, int ww, int lane) {
    int kw = ww & 255, c = ww >> 8;
    int k = (kw << 6) + lane;
    float4 d = P.PDs[k];
    float y = d.y * INV2L, z = d.z * INV2L;
    int yc0, yc1, zb0, zb1; wave_range(y, z, yc0, yc1, zb0, zb1);
    float acc = theta_acc(P.PSs, P.OFF, d, yc0, yc1, zb0, zb1, c, 4);
    atomicAdd(&P.thc[k], acc);
}

__device__ __forceinline__ void do_thb(Ptrs P, int ww, int lane) {
    int kw = ww & 255, b = ww >> 8;
    int k = (kw << 6) + lane;
    float4 d = P.PDs[k];
    float y = d.y * INV2L, z = d.z * INV2L;
    int yc0, yc1, zb0, zb1; wave_range(y, z, yc0, yc1, zb0, zb1);
    float acc = theta_acc(P.PSs + ((b + 1) << 10), P.OFF + (b + 1) * 385, d,
                          yc0, yc1, zb0, zb1, 0, 1);
    float v = acc * P.thc[k];
    for (int o = 32; o; o >>= 1) v += __shfl_xor(v, o, 64);
    if (lane == 0) atomicAdd(&P.prod[b], v);
}

// ---------------- fused cooperative kernel (1 dispatch) ----------------
__global__ void __launch_bounds__(256, 4)
k_fused(const float* C1, const float* C, const float* dom, float* out, char* ws) {
    cg::grid_group g = cg::this_grid();
    Ptrs P = mk(ws);
    int gsize = gridDim.x * 256;
    int gtid = blockIdx.x * 256 + threadIdx.x;
    int lane = threadIdx.x & 63;
    int w = gtid >> 6, W = gsize >> 6;

    // P0: zero thc + SH + KH (contiguous) and prod
    int* zr = (int*)(ws + O_THC);
    for (int i = gtid; i < 23296; i += gsize) zr[i] = 0;
    if (gtid < 16) P.prod[gtid] = 0.0f;
    g.sync();
    // P1: histogram
    for (int i = gtid; i < 33792; i += gsize) do_hist(P, C1, C, dom, i);
    g.sync();
    // P2: prefix scans (18 waves)
    if (w < 18) do_scan(P, w, lane);
    g.sync();
    // P3: scatter + fold
    for (int i = gtid; i < 33792; i += gsize) do_scat(P, C1, C, dom, i);
    g.sync();
    // P4: theta_C (4-way source split)
    for (int ww = w; ww < 1024; ww += W) do_thc(P, ww, lane);
    g.sync();
    // P5: theta_B * theta_C, reduce
    for (int ww = w; ww < 4096; ww += W) do_thb(P, ww, lane);
    g.sync();
    // P6: finalize
    if (gtid < 16) {
        float dv = P.prod[gtid] * SCALE;
        dv = fminf(fmaxf(dv, 0.0f), 1.0f);
        out[gtid] = 1.0f - dv;
    }
}

// ---------------- fallback multi-kernel path ----------------
__global__ void __launch_bounds__(256) k_zero(char* ws) {
    Ptrs P = mk(ws);
    int i = blockIdx.x * 256 + threadIdx.x;
    if (i < 23296) ((int*)(ws + O_THC))[i] = 0;
    if (i < 16) P.prod[i] = 0.0f;
}
__global__ void __launch_bounds__(256) k_hist(char* ws, const float* C1, const float* C,
                                              const float* dom) {
    int i = blockIdx.x * 256 + threadIdx.x;
    if (i < 33792) do_hist(mk(ws), C1, C, dom, i);
}
__global__ void __launch_bounds__(64) k_scan(char* ws) {
    do_scan(mk(ws), blockIdx.x, threadIdx.x);
}
__global__ void __launch_bounds__(256) k_scat(char* ws, const float* C1, const float* C,
                                              const float* dom) {
    int i = blockIdx.x * 256 + threadIdx.x;
    if (i < 33792) do_scat(mk(ws), C1, C, dom, i);
}
__global__ void __launch_bounds__(64) k_thc_f(char* ws) {
    do_thc(mk(ws), (blockIdx.y << 8) | blockIdx.x, threadIdx.x);
}
__global__ void __launch_bounds__(64) k_thb_f(char* ws) {
    do_thb(mk(ws), (blockIdx.y << 8) | blockIdx.x, threadIdx.x);
}
__global__ void __launch_bounds__(64) k_fin(char* ws, float* out) {
    Ptrs P = mk(ws);
    int t = threadIdx.x;
    if (t < 16) {
        float dv = P.prod[t] * SCALE;
        dv = fminf(fmaxf(dv, 0.0f), 1.0f);
        out[t] = 1.0f - dv;
    }
}

extern "C" void kernel_launch(void* const* d_in, const int* in_sizes, int n_in,
                              void* d_out, int out_size, void* d_ws, size_t ws_size,
                              hipStream_t stream) {
    const float* C1  = (const float*)d_in[0];
    const float* C   = (const float*)d_in[1];
    const float* dom = (const float*)d_in[2];
    float* out = (float*)d_out;
    char* ws = (char*)d_ws;

    int nb = 0;
    hipError_t oe = hipOccupancyMaxActiveBlocksPerMultiprocessor(&nb, (const void*)k_fused,
                                                                 256, 0);
    if (oe != hipSuccess || nb < 1) nb = 4;
    int G = nb * 256; if (G > 1024) G = 1024;

    void* args[5] = {(void*)&C1, (void*)&C, (void*)&dom, (void*)&out, (void*)&ws};
    hipError_t e = hipLaunchCooperativeKernel((const void*)k_fused, dim3(G), dim3(256),
                                              args, 0, stream);
    if (e != hipSuccess) {
        k_zero<<<92, 256, 0, stream>>>(ws);
        k_hist<<<132, 256, 0, stream>>>(ws, C1, C, dom);
        k_scan<<<18, 64, 0, stream>>>(ws);
        k_scat<<<132, 256, 0, stream>>>(ws, C1, C, dom);
        k_thc_f<<<dim3(256, 4), 64, 0, stream>>>(ws);
        k_thb_f<<<dim3(256, 16), 64, 0, stream>>>(ws);
        k_fin<<<1, 64, 0, stream>>>(ws, out);
    }
}

// Round 4
// 171.193 us; speedup vs baseline: 4.5476x; 4.5476x over previous
//
#include <hip/hip_runtime.h>
#include <math.h>

// exp(-2*pi*r^2) == exp2(-L*r^2)
#define LCONST 9.064720283654388f
#define INV2L  (1.0f / (2.0f * LCONST))
#define RC     1.6f                       // cutoff: exp(-2pi*2.56) ~ 1.1e-7
#define SCALE  4.76837158203125e-4f       // A * V / 1024 = 8*(1000/16384)/1024
#define NK     16384

// ws layout (bytes) — total ~700 KB (R1 proved >= 802880 available)
#define O_PSS   0u          // 17408 float4 sorted sources: ent 0 = C, 1..16 = C1 batches
#define O_PDS   278528u     // 16384 float4 sorted folded grid points
#define O_OFF   540672u     // 18*385 int bucket offsets (+sentinel); ent 17 = dom (unused later)
#define O_THCP  568448u     // 2*16384 float theta_C partials
#define O_PROD  699520u     // 16 float
#define O_DONE  699584u     // 1 int completion counter

__device__ __forceinline__ float fexp2(float x) { return __builtin_amdgcn_exp2f(x); }

__device__ __forceinline__ int ckey(float y, float z) {
    int yc = (int)(y * 0.6f);  yc = yc < 0 ? 0 : (yc > 5 ? 5 : yc);
    int zb = (int)(z * 6.4f);  zb = zb < 0 ? 0 : (zb > 63 ? 63 : zb);
    return (yc << 6) + zb;
}

// ---- sort: one block per entity; hist/scan/scatter all block-local ----
__global__ void __launch_bounds__(1024) k_sort(const float* __restrict__ C1,
                                               const float* __restrict__ C,
                                               const float* __restrict__ dom,
                                               char* __restrict__ ws) {
    float4* PSs = (float4*)(ws + O_PSS);
    float4* PDs = (float4*)(ws + O_PDS);
    int*    OFF = (int*)(ws + O_OFF);
    float*  prod = (float*)(ws + O_PROD);
    int*    done = (int*)(ws + O_DONE);

    __shared__ int hist[384], cur[384];
    int e = blockIdx.x;            // 0 = C, 1..16 = C1 batch e-1, 17 = dom
    int tid = threadIdx.x;
    if (tid < 384) hist[tid] = 0;
    if (e == 0 && tid < 16) prod[tid] = 0.0f;
    if (e == 0 && tid == 1023) *done = 0;
    __syncthreads();

    int npts = (e == 17) ? NK : 1024;
    const float* src = (e == 0) ? C : (e == 17 ? dom : C1 + 3072 * (e - 1));

    for (int i = tid; i < npts; i += 1024) {
        float y = src[3*i+1], z = src[3*i+2];
        atomicAdd(&hist[ckey(y, z)], 1);
    }
    __syncthreads();

    if (tid < 64) {                 // wave 0: scan 384 buckets (6 per lane)
        int lane = tid, base = lane * 6;
        int c[6], pre[6], tot = 0;
        #pragma unroll
        for (int j = 0; j < 6; ++j) { c[j] = hist[base + j]; pre[j] = tot; tot += c[j]; }
        int incl = tot;
        for (int o = 1; o < 64; o <<= 1) { int t = __shfl_up(incl, o, 64); if (lane >= o) incl += t; }
        int excl = incl - tot;
        #pragma unroll
        for (int j = 0; j < 6; ++j) {
            OFF[e * 385 + base + j] = excl + pre[j];
            cur[base + j] = excl + pre[j];
        }
        if (lane == 63) OFF[e * 385 + 384] = incl;
    }
    __syncthreads();

    for (int i = tid; i < npts; i += 1024) {
        float x = src[3*i], y = src[3*i+1], z = src[3*i+2];
        float q = x*x + y*y + z*z;
        int pos = atomicAdd(&cur[ckey(y, z)], 1);
        if (e == 17)
            PDs[pos] = make_float4(2.0f*LCONST*x, 2.0f*LCONST*y, 2.0f*LCONST*z, -LCONST*q);
        else
            PSs[(e << 10) + pos] = make_float4(x, y, z, -LCONST * q);
    }
}

// ---- shared inner machinery ----
__device__ __forceinline__ void wave_range(float y, float z, int& yc0, int& yc1,
                                           int& zb0, int& zb1) {
    float ymn = y, ymx = y, zmn = z, zmx = z;
    for (int o = 32; o; o >>= 1) {
        ymn = fminf(ymn, __shfl_xor(ymn, o, 64)); ymx = fmaxf(ymx, __shfl_xor(ymx, o, 64));
        zmn = fminf(zmn, __shfl_xor(zmn, o, 64)); zmx = fmaxf(zmx, __shfl_xor(zmx, o, 64));
    }
    yc0 = max(0, (int)floorf((ymn - RC) * 0.6f));
    yc1 = min(5, (int)floorf((ymx + RC) * 0.6f));
    zb0 = max(0, (int)floorf((zmn - RC) * 6.4f));
    zb1 = min(63, (int)floorf((zmx + RC) * 6.4f));
    yc0 = __builtin_amdgcn_readfirstlane(yc0); yc1 = __builtin_amdgcn_readfirstlane(yc1);
    zb0 = __builtin_amdgcn_readfirstlane(zb0); zb1 = __builtin_amdgcn_readfirstlane(zb1);
}

__device__ __forceinline__ float theta_acc(const float4* __restrict__ P,
                                           const int* __restrict__ otab, float4 d,
                                           int yc0, int yc1, int zb0, int zb1,
                                           int c, int nc) {
    float acc = 0.0f;
    for (int yc = yc0; yc <= yc1; ++yc) {
        int n0 = otab[(yc << 6) + zb0];
        int n1 = otab[(yc << 6) + zb1 + 1];
        int len = n1 - n0;
        int lo = n0 + (len * c) / nc, hi = n0 + (len * (c + 1)) / nc;
        #pragma unroll 4
        for (int n = lo; n < hi; ++n) {
            float4 p = P[n];
            acc += fexp2(fmaf(d.x, p.x, fmaf(d.y, p.y, fmaf(d.z, p.z, d.w + p.w))));
        }
    }
    return acc;
}

// ---- theta_C partials: 512 wave tasks (256 k-groups x 2 source chunks) ----
__global__ void __launch_bounds__(256) k_thc(char* __restrict__ ws) {
    const float4* PSs = (const float4*)(ws + O_PSS);
    const float4* PDs = (const float4*)(ws + O_PDS);
    const int*    OFF = (const int*)(ws + O_OFF);
    float*       thcp = (float*)(ws + O_THCP);

    int lane = threadIdx.x & 63;
    int ww = blockIdx.x * 4 + (threadIdx.x >> 6);   // 0..511
    int kw = ww & 255, c = ww >> 8;
    int k = (kw << 6) + lane;
    float4 d = PDs[k];
    float y = d.y * INV2L, z = d.z * INV2L;
    int yc0, yc1, zb0, zb1; wave_range(y, z, yc0, yc1, zb0, zb1);
    thcp[c * NK + k] = theta_acc(PSs, OFF, d, yc0, yc1, zb0, zb1, c, 2);
}

// ---- theta_B * theta_C reduce + fused finalize: 4096 wave tasks ----
__global__ void __launch_bounds__(256) k_thb(char* __restrict__ ws, float* __restrict__ out) {
    const float4* PSs = (const float4*)(ws + O_PSS);
    const float4* PDs = (const float4*)(ws + O_PDS);
    const int*    OFF = (const int*)(ws + O_OFF);
    const float* thcp = (const float*)(ws + O_THCP);
    float*       prod = (float*)(ws + O_PROD);
    int*         done = (int*)(ws + O_DONE);

    int lane = threadIdx.x & 63;
    int ww = blockIdx.x * 4 + (threadIdx.x >> 6);   // 0..4095
    int kw = ww & 255, b = ww >> 8;
    int k = (kw << 6) + lane;
    float4 d = PDs[k];
    float y = d.y * INV2L, z = d.z * INV2L;
    int yc0, yc1, zb0, zb1; wave_range(y, z, yc0, yc1, zb0, zb1);
    float acc = theta_acc(PSs + ((b + 1) << 10), OFF + (b + 1) * 385,
                          d, yc0, yc1, zb0, zb1, 0, 1);
    float v = acc * (thcp[k] + thcp[NK + k]);
    for (int o = 32; o; o >>= 1) v += __shfl_xor(v, o, 64);
    if (lane == 0) atomicAdd(prod + b, v);

    __syncthreads();
    if (threadIdx.x == 0) {
        __threadfence();
        int old = atomicAdd(done, 1);
        if (old == (int)gridDim.x - 1) {            // last block finalizes
            #pragma unroll
            for (int j = 0; j < 16; ++j) {
                float pv = __hip_atomic_load(prod + j, __ATOMIC_ACQUIRE,
                                             __HIP_MEMORY_SCOPE_AGENT);
                float dv = pv * SCALE;
                dv = fminf(fmaxf(dv, 0.0f), 1.0f);
                out[j] = 1.0f - dv;
            }
        }
    }
}

extern "C" void kernel_launch(void* const* d_in, const int* in_sizes, int n_in,
                              void* d_out, int out_size, void* d_ws, size_t ws_size,
                              hipStream_t stream) {
    const float* C1  = (const float*)d_in[0];   // (16,1024,3)
    const float* C   = (const float*)d_in[1];   // (1024,3)
    const float* dom = (const float*)d_in[2];   // (16384,3)
    float* out = (float*)d_out;                 // (16,)
    char* ws = (char*)d_ws;

    k_sort<<<18, 1024, 0, stream>>>(C1, C, dom, ws);
    k_thc<<<128, 256, 0, stream>>>(ws);
    k_thb<<<1024, 256, 0, stream>>>(ws, out);
}

// Round 5
// 156.512 us; speedup vs baseline: 4.9742x; 1.0938x over previous
//
#include <hip/hip_runtime.h>
#include <math.h>

// exp(-2*pi*r^2) == exp2(-L*r^2)
#define LCONST 9.064720283654388f
#define INV2L  (1.0f / (2.0f * LCONST))
#define RC     1.6f                       // cutoff: exp(-2pi*2.56) ~ 1.1e-7
#define SCALE  4.76837158203125e-4f       // A * V / 1024 = 8*(1000/16384)/1024
#define NK     16384
#define MAXG   262                        // max grid-point groups (256 + 6 cell tails)

// ws layout (bytes)
#define O_PSS   0u          // 17408 float4 sorted sources: ent 0 = C, 1..16 = C1 batches
#define O_PDS   278528u     // 16384 float4 sorted folded grid points
#define O_OFF   540672u     // 18*385 int bucket offsets (+sentinel); ent 17 = dom
#define O_THCP  568448u     // 4*16384 float theta_C partials
#define O_PROD  830592u     // 16 float
#define O_DONE  830656u     // 1 int completion counter
#define O_NG    830660u     // 1 int group count
#define O_GT    830664u     // MAXG ints packed group table: start|cnt<<15|yc<<22

__device__ __forceinline__ float fexp2(float x) { return __builtin_amdgcn_exp2f(x); }

__device__ __forceinline__ int ckey(float y, float z) {
    int yc = (int)(y * 0.6f);  yc = yc < 0 ? 0 : (yc > 5 ? 5 : yc);
    int zb = (int)(z * 6.4f);  zb = zb < 0 ? 0 : (zb > 63 ? 63 : zb);
    return (yc << 6) + zb;
}

// ---- sort: one block per entity; hist/scan/scatter all block-local ----
__global__ void __launch_bounds__(1024) k_sort(const float* __restrict__ C1,
                                               const float* __restrict__ C,
                                               const float* __restrict__ dom,
                                               char* __restrict__ ws) {
    float4* PSs = (float4*)(ws + O_PSS);
    float4* PDs = (float4*)(ws + O_PDS);
    int*    OFF = (int*)(ws + O_OFF);
    float*  prod = (float*)(ws + O_PROD);
    int*    done = (int*)(ws + O_DONE);
    int*    NGp  = (int*)(ws + O_NG);
    int*    GT   = (int*)(ws + O_GT);

    __shared__ int hist[384], cur[384];
    int e = blockIdx.x;            // 0 = C, 1..16 = C1 batch e-1, 17 = dom
    int tid = threadIdx.x;
    if (tid < 384) hist[tid] = 0;
    if (e == 0 && tid < 16) prod[tid] = 0.0f;
    if (e == 0 && tid == 1023) *done = 0;
    __syncthreads();

    int npts = (e == 17) ? NK : 1024;
    const float* src = (e == 0) ? C : (e == 17 ? dom : C1 + 3072 * (e - 1));

    for (int i = tid; i < npts; i += 1024) {
        float y = src[3*i+1], z = src[3*i+2];
        atomicAdd(&hist[ckey(y, z)], 1);
    }
    __syncthreads();

    if (tid < 64) {                 // wave 0: scan 384 buckets (6 per lane)
        int lane = tid, base = lane * 6;
        int c[6], pre[6], tot = 0;
        #pragma unroll
        for (int j = 0; j < 6; ++j) { c[j] = hist[base + j]; pre[j] = tot; tot += c[j]; }
        int incl = tot;
        for (int o = 1; o < 64; o <<= 1) { int t = __shfl_up(incl, o, 64); if (lane >= o) incl += t; }
        int excl = incl - tot;
        #pragma unroll
        for (int j = 0; j < 6; ++j) {
            OFF[e * 385 + base + j] = excl + pre[j];
            cur[base + j] = excl + pre[j];
        }
        if (lane == 63) OFF[e * 385 + 384] = incl;
    }
    __syncthreads();

    for (int i = tid; i < npts; i += 1024) {
        float x = src[3*i], y = src[3*i+1], z = src[3*i+2];
        float q = x*x + y*y + z*z;
        int pos = atomicAdd(&cur[ckey(y, z)], 1);
        if (e == 17)
            PDs[pos] = make_float4(2.0f*LCONST*x, 2.0f*LCONST*y, 2.0f*LCONST*z, -LCONST*q);
        else
            PSs[(e << 10) + pos] = make_float4(x, y, z, -LCONST * q);
    }

    // group table: y-cell-aligned groups of <=64 grid points (no cell straddling)
    if (e == 17) {
        __syncthreads();
        if (tid == 0) {
            int ng = 0;
            #pragma unroll
            for (int yc = 0; yc < 6; ++yc) {
                int s  = OFF[17 * 385 + (yc << 6)];
                int en = (yc == 5) ? NK : OFF[17 * 385 + ((yc + 1) << 6)];
                for (int p = s; p < en; p += 64) {
                    int cnt = min(64, en - p);
                    GT[ng++] = p | (cnt << 15) | (yc << 22);
                }
            }
            *NGp = ng;
        }
    }
}

// ---- shared inner machinery ----
__device__ __forceinline__ void zrange(float z, int& zb0, int& zb1) {
    float zmn = z, zmx = z;
    for (int o = 32; o; o >>= 1) {
        zmn = fminf(zmn, __shfl_xor(zmn, o, 64));
        zmx = fmaxf(zmx, __shfl_xor(zmx, o, 64));
    }
    zb0 = max(0, (int)floorf((zmn - RC) * 6.4f));
    zb1 = min(63, (int)floorf((zmx + RC) * 6.4f));
    zb0 = __builtin_amdgcn_readfirstlane(zb0);
    zb1 = __builtin_amdgcn_readfirstlane(zb1);
}

__device__ __forceinline__ float theta_acc(const float4* __restrict__ P,
                                           const int* __restrict__ otab, float4 d,
                                           int yc0, int yc1, int zb0, int zb1,
                                           int c, int nc) {
    float acc = 0.0f;
    for (int yc = yc0; yc <= yc1; ++yc) {
        int n0 = otab[(yc << 6) + zb0];
        int n1 = otab[(yc << 6) + zb1 + 1];
        int len = n1 - n0;
        int lo = n0 + (len * c) / nc, hi = n0 + (len * (c + 1)) / nc;
        #pragma unroll 4
        for (int n = lo; n < hi; ++n) {
            float4 p = P[n];
            acc += fexp2(fmaf(d.x, p.x, fmaf(d.y, p.y, fmaf(d.z, p.z, d.w + p.w))));
        }
    }
    return acc;
}

// unpack group, load point (masked lanes duplicate last point), return valid mask
__device__ __forceinline__ bool load_group(const float4* PDs, const int* GT, int gi,
                                           int lane, float4& d, int& k,
                                           int& yc0, int& yc1, int& zb0, int& zb1) {
    int packed = GT[gi];
    int start = packed & 0x7FFF, cnt = (packed >> 15) & 0x7F, yc = packed >> 22;
    bool valid = lane < cnt;
    k = start + (valid ? lane : cnt - 1);
    d = PDs[k];
    yc0 = max(0, yc - 1); yc1 = min(5, yc + 1);
    zrange(d.z * INV2L, zb0, zb1);
    return valid;
}

// ---- theta_C partials: ng*4 wave tasks (4-way source split) ----
__global__ void __launch_bounds__(256) k_thc(char* __restrict__ ws) {
    const float4* PSs = (const float4*)(ws + O_PSS);
    const float4* PDs = (const float4*)(ws + O_PDS);
    const int*    OFF = (const int*)(ws + O_OFF);
    const int*    GT  = (const int*)(ws + O_GT);
    float*       thcp = (float*)(ws + O_THCP);
    int ng = *(const int*)(ws + O_NG);

    int lane = threadIdx.x & 63;
    int task = blockIdx.x * 4 + (threadIdx.x >> 6);
    if (task >= (ng << 2)) return;
    int gi = task >> 2, c = task & 3;

    float4 d; int k, yc0, yc1, zb0, zb1;
    bool valid = load_group(PDs, GT, gi, lane, d, k, yc0, yc1, zb0, zb1);
    float acc = theta_acc(PSs, OFF, d, yc0, yc1, zb0, zb1, c, 4);
    if (valid) thcp[c * NK + k] = acc;
}

// ---- theta_B * theta_C reduce + fused finalize: ng*16 wave tasks ----
__global__ void __launch_bounds__(256) k_thb(char* __restrict__ ws, float* __restrict__ out) {
    const float4* PSs = (const float4*)(ws + O_PSS);
    const float4* PDs = (const float4*)(ws + O_PDS);
    const int*    OFF = (const int*)(ws + O_OFF);
    const int*    GT  = (const int*)(ws + O_GT);
    const float* thcp = (const float*)(ws + O_THCP);
    float*       prod = (float*)(ws + O_PROD);
    int*         done = (int*)(ws + O_DONE);
    int ng = *(const int*)(ws + O_NG);

    int lane = threadIdx.x & 63;
    int task = blockIdx.x * 4 + (threadIdx.x >> 6);
    if (task < (ng << 4)) {
        int gi = task >> 4, b = task & 15;
        float4 d; int k, yc0, yc1, zb0, zb1;
        bool valid = load_group(PDs, GT, gi, lane, d, k, yc0, yc1, zb0, zb1);
        float acc = theta_acc(PSs + ((b + 1) << 10), OFF + (b + 1) * 385,
                              d, yc0, yc1, zb0, zb1, 0, 1);
        float tc = thcp[k] + thcp[NK + k] + thcp[2 * NK + k] + thcp[3 * NK + k];
        float v = valid ? acc * tc : 0.0f;
        for (int o = 32; o; o >>= 1) v += __shfl_xor(v, o, 64);
        if (lane == 0) atomicAdd(prod + b, v);
    }
    __syncthreads();
    if (threadIdx.x == 0) {
        __threadfence();
        int old = atomicAdd(done, 1);
        if (old == (int)gridDim.x - 1) {            // last block finalizes
            #pragma unroll
            for (int j = 0; j < 16; ++j) {
                float pv = __hip_atomic_load(prod + j, __ATOMIC_ACQUIRE,
                                             __HIP_MEMORY_SCOPE_AGENT);
                float dv = pv * SCALE;
                dv = fminf(fmaxf(dv, 0.0f), 1.0f);
                out[j] = 1.0f - dv;
            }
        }
    }
}

extern "C" void kernel_launch(void* const* d_in, const int* in_sizes, int n_in,
                              void* d_out, int out_size, void* d_ws, size_t ws_size,
                              hipStream_t stream) {
    const float* C1  = (const float*)d_in[0];   // (16,1024,3)
    const float* C   = (const float*)d_in[1];   // (1024,3)
    const float* dom = (const float*)d_in[2];   // (16384,3)
    float* out = (float*)d_out;                 // (16,)
    char* ws = (char*)d_ws;

    k_sort<<<18, 1024, 0, stream>>>(C1, C, dom, ws);
    k_thc<<<MAXG, 256, 0, stream>>>(ws);                    // covers ng*4 waves
    k_thb<<<(MAXG * 16 + 3) / 4, 256, 0, stream>>>(ws, out); // covers ng*16 waves
}